// Round 1
// baseline (280.191 us; speedup 1.0000x reference)
//
#include <hip/hip_runtime.h>

// MultiCamNoiseCropV3Prompter: out = x + prompt broadcast over T frames.
// prompt[b,c,i,j] built from small pad tensors via region-wise 1D bilinear
// interp (PyTorch align_corners=False semantics). Memory-bound: 308 MB
// compulsory x-read + out-write traffic; pads (~1.3 MB) are L2-resident.

#define PP 30
#define SS 224
#define CROPC 164
#define BB 16
#define TT 16

__device__ __forceinline__ void interp1d(float pos, float in_size, int in_size_i,
                                         int out_size, int& i0, int& i1, float& w) {
    float scale = in_size / (float)out_size;
    float f = fmaxf((pos + 0.5f) * scale - 0.5f, 0.0f);
    i0 = (int)floorf(f);
    w = f - (float)i0;
    i1 = min(i0 + 1, in_size_i - 1);
}

__global__ void __launch_bounds__(256)
prompt_add_kernel(const float* __restrict__ x,
                  const float* __restrict__ pu,   // [3,3,2P,S]
                  const float* __restrict__ pd,   // [3,3,P,S]
                  const float* __restrict__ pl,   // [3,3,CROP,2P]
                  const float* __restrict__ pr,   // [3,3,CROP,P]
                  const int* __restrict__ cam_views,
                  const int* __restrict__ offs_r,
                  const int* __restrict__ offs_d,
                  float* __restrict__ out) {
    const int J4 = SS / 4;  // 56 float4 per row
    int idx = blockIdx.x * blockDim.x + threadIdx.x;
    const int total = BB * 3 * SS * J4;
    if (idx >= total) return;

    int j4 = idx % J4;
    int tmp = idx / J4;
    int i = tmp % SS;
    tmp /= SS;
    int c = tmp % 3;
    int b = tmp / 3;

    const int cam = cam_views[b];
    const int off_r = offs_r[b];
    const int off_d = offs_d[b];
    const int off_l = 2 * PP - off_r;
    const int off_u = 2 * PP - off_d;

    const float* puc = pu + (size_t)(cam * 3 + c) * (2 * PP) * SS;
    const float* pdc = pd + (size_t)(cam * 3 + c) * PP * SS;
    const float* plc = pl + (size_t)(cam * 3 + c) * CROPC * (2 * PP);
    const float* prc = pr + (size_t)(cam * 3 + c) * CROPC * PP;

    const int j0 = j4 * 4;
    float pv[4];

    if (i < off_u) {
        // vertical interp over pad_up rows (in_size = 2P = 60)
        int r0, r1; float w;
        interp1d((float)i, (float)(2 * PP), 2 * PP, off_u, r0, r1, w);
        const float* a = puc + (size_t)r0 * SS + j0;
        const float* bp = puc + (size_t)r1 * SS + j0;
        #pragma unroll
        for (int k = 0; k < 4; k++)
            pv[k] = a[k] * (1.0f - w) + bp[k] * w;
    } else if (i >= SS - off_d) {
        // vertical interp over pad_down rows (in_size = P = 30)
        int r0, r1; float w;
        interp1d((float)(i - (SS - off_d)), (float)PP, PP, off_d, r0, r1, w);
        const float* a = pdc + (size_t)r0 * SS + j0;
        const float* bp = pdc + (size_t)r1 * SS + j0;
        #pragma unroll
        for (int k = 0; k < 4; k++)
            pv[k] = a[k] * (1.0f - w) + bp[k] * w;
    } else {
        // middle rows: horizontal interp from pad_left / pad_right / zero
        const int r = i - off_u;  // in [0, CROP)
        const float* plr = plc + (size_t)r * (2 * PP);
        const float* prr = prc + (size_t)r * PP;
        #pragma unroll
        for (int k = 0; k < 4; k++) {
            int j = j0 + k;
            float v = 0.0f;
            if (j < off_l) {
                int c0, c1; float w;
                interp1d((float)j, (float)(2 * PP), 2 * PP, off_l, c0, c1, w);
                v = plr[c0] * (1.0f - w) + plr[c1] * w;
            } else if (j >= SS - off_r) {
                int c0, c1; float w;
                interp1d((float)(j - (SS - off_r)), (float)PP, PP, off_r, c0, c1, w);
                v = prr[c0] * (1.0f - w) + prr[c1] * w;
            }
            pv[k] = v;
        }
    }

    // stream the T frames: float4 load/add/store, coalesced
    size_t base = ((size_t)(b * 3 + c) * TT) * (SS * SS) + (size_t)i * SS + j0;
    #pragma unroll
    for (int t = 0; t < TT; t++) {
        size_t off = base + (size_t)t * (SS * SS);
        float4 xv = *reinterpret_cast<const float4*>(x + off);
        float4 ov;
        ov.x = xv.x + pv[0];
        ov.y = xv.y + pv[1];
        ov.z = xv.z + pv[2];
        ov.w = xv.w + pv[3];
        *reinterpret_cast<float4*>(out + off) = ov;
    }
}

extern "C" void kernel_launch(void* const* d_in, const int* in_sizes, int n_in,
                              void* d_out, int out_size, void* d_ws, size_t ws_size,
                              hipStream_t stream) {
    const float* x  = (const float*)d_in[0];
    const float* pu = (const float*)d_in[1];
    const float* pd = (const float*)d_in[2];
    const float* pl = (const float*)d_in[3];
    const float* pr = (const float*)d_in[4];
    const int* cam  = (const int*)d_in[5];
    const int* orr  = (const int*)d_in[6];
    const int* od   = (const int*)d_in[7];
    float* out = (float*)d_out;

    const int total = BB * 3 * SS * (SS / 4);  // 602112 threads
    const int threads = 256;
    const int blocks = (total + threads - 1) / threads;  // 2352
    prompt_add_kernel<<<blocks, threads, 0, stream>>>(x, pu, pd, pl, pr, cam, orr, od, out);
}

// Round 2
// 273.301 us; speedup vs baseline: 1.0252x; 1.0252x over previous
//
#include <hip/hip_runtime.h>

// MultiCamNoiseCropV3Prompter: out = x + prompt broadcast over T frames.
// R2 structure: (1) materialize prompt [B,3,S,S] (2.4 MB) into d_ws;
// (2) pure streaming add: 1 x-load + 1 prompt-load (L2/L3-hit) + 1 store
// per thread. R1's fused T-loop was latency-bound at 2.5 TB/s (VGPR=32
// capped in-flight loads); the stream shape hides latency with wave count.

#define PP 30
#define SS 224
#define CROPC 164
#define BB 16
#define TT 16

__device__ __forceinline__ void interp1d(float pos, float in_size, int in_size_i,
                                         int out_size, int& i0, int& i1, float& w) {
    float scale = in_size / (float)out_size;
    float f = fmaxf((pos + 0.5f) * scale - 0.5f, 0.0f);
    i0 = (int)floorf(f);
    w = f - (float)i0;
    i1 = min(i0 + 1, in_size_i - 1);
}

// Kernel 1: build prompt[b,c,i,j] into ws (float, [B,3,S,S]).
__global__ void __launch_bounds__(256)
prompt_build_kernel(const float* __restrict__ pu,   // [3,3,2P,S]
                    const float* __restrict__ pd,   // [3,3,P,S]
                    const float* __restrict__ pl,   // [3,3,CROP,2P]
                    const float* __restrict__ pr,   // [3,3,CROP,P]
                    const int* __restrict__ cam_views,
                    const int* __restrict__ offs_r,
                    const int* __restrict__ offs_d,
                    float* __restrict__ prompt) {
    const int J4 = SS / 4;  // 56
    int idx = blockIdx.x * blockDim.x + threadIdx.x;
    const int total = BB * 3 * SS * J4;
    if (idx >= total) return;

    int j4 = idx % J4;
    int tmp = idx / J4;
    int i = tmp % SS;
    tmp /= SS;
    int c = tmp % 3;
    int b = tmp / 3;

    const int cam = cam_views[b];
    const int off_r = offs_r[b];
    const int off_d = offs_d[b];
    const int off_l = 2 * PP - off_r;
    const int off_u = 2 * PP - off_d;

    const float* puc = pu + (size_t)(cam * 3 + c) * (2 * PP) * SS;
    const float* pdc = pd + (size_t)(cam * 3 + c) * PP * SS;
    const float* plc = pl + (size_t)(cam * 3 + c) * CROPC * (2 * PP);
    const float* prc = pr + (size_t)(cam * 3 + c) * CROPC * PP;

    const int j0 = j4 * 4;
    float pv[4];

    if (i < off_u) {
        int r0, r1; float w;
        interp1d((float)i, (float)(2 * PP), 2 * PP, off_u, r0, r1, w);
        const float* a = puc + (size_t)r0 * SS + j0;
        const float* bp = puc + (size_t)r1 * SS + j0;
        #pragma unroll
        for (int k = 0; k < 4; k++)
            pv[k] = a[k] * (1.0f - w) + bp[k] * w;
    } else if (i >= SS - off_d) {
        int r0, r1; float w;
        interp1d((float)(i - (SS - off_d)), (float)PP, PP, off_d, r0, r1, w);
        const float* a = pdc + (size_t)r0 * SS + j0;
        const float* bp = pdc + (size_t)r1 * SS + j0;
        #pragma unroll
        for (int k = 0; k < 4; k++)
            pv[k] = a[k] * (1.0f - w) + bp[k] * w;
    } else {
        const int r = i - off_u;
        const float* plr = plc + (size_t)r * (2 * PP);
        const float* prr = prc + (size_t)r * PP;
        #pragma unroll
        for (int k = 0; k < 4; k++) {
            int j = j0 + k;
            float v = 0.0f;
            if (j < off_l) {
                int c0, c1; float w;
                interp1d((float)j, (float)(2 * PP), 2 * PP, off_l, c0, c1, w);
                v = plr[c0] * (1.0f - w) + plr[c1] * w;
            } else if (j >= SS - off_r) {
                int c0, c1; float w;
                interp1d((float)(j - (SS - off_r)), (float)PP, PP, off_r, c0, c1, w);
                v = prr[c0] * (1.0f - w) + prr[c1] * w;
            }
            pv[k] = v;
        }
    }

    float4 o; o.x = pv[0]; o.y = pv[1]; o.z = pv[2]; o.w = pv[3];
    *reinterpret_cast<float4*>(prompt + (size_t)idx * 4) = o;
}

// Kernel 2: out[idx] = x[idx] + prompt[bc,p]; one float4 per thread.
__global__ void __launch_bounds__(256)
stream_add_kernel(const float* __restrict__ x,
                  const float* __restrict__ prompt,
                  float* __restrict__ out) {
    const int P4 = SS * SS / 4;  // 12544 float4 per frame
    int idx = blockIdx.x * blockDim.x + threadIdx.x;  // < 768 * P4
    int p4 = idx % P4;
    int frame = idx / P4;      // (b*3+c)*T + t
    int bc = frame / TT;

    const float4 xv = *reinterpret_cast<const float4*>(x + (size_t)idx * 4);
    const float4 pv = *reinterpret_cast<const float4*>(prompt + ((size_t)bc * P4 + p4) * 4);
    float4 ov;
    ov.x = xv.x + pv.x;
    ov.y = xv.y + pv.y;
    ov.z = xv.z + pv.z;
    ov.w = xv.w + pv.w;
    *reinterpret_cast<float4*>(out + (size_t)idx * 4) = ov;
}

// Fallback (R1 fused) in case ws_size is too small for the prompt buffer.
__global__ void __launch_bounds__(256)
fused_kernel(const float* __restrict__ x,
             const float* __restrict__ pu, const float* __restrict__ pd,
             const float* __restrict__ pl, const float* __restrict__ pr,
             const int* __restrict__ cam_views,
             const int* __restrict__ offs_r, const int* __restrict__ offs_d,
             float* __restrict__ out) {
    const int J4 = SS / 4;
    int idx = blockIdx.x * blockDim.x + threadIdx.x;
    const int total = BB * 3 * SS * J4;
    if (idx >= total) return;
    int j4 = idx % J4;
    int tmp = idx / J4;
    int i = tmp % SS;
    tmp /= SS;
    int c = tmp % 3;
    int b = tmp / 3;
    const int cam = cam_views[b];
    const int off_r = offs_r[b];
    const int off_d = offs_d[b];
    const int off_l = 2 * PP - off_r;
    const int off_u = 2 * PP - off_d;
    const float* puc = pu + (size_t)(cam * 3 + c) * (2 * PP) * SS;
    const float* pdc = pd + (size_t)(cam * 3 + c) * PP * SS;
    const float* plc = pl + (size_t)(cam * 3 + c) * CROPC * (2 * PP);
    const float* prc = pr + (size_t)(cam * 3 + c) * CROPC * PP;
    const int j0 = j4 * 4;
    float pv[4];
    if (i < off_u) {
        int r0, r1; float w;
        interp1d((float)i, (float)(2 * PP), 2 * PP, off_u, r0, r1, w);
        const float* a = puc + (size_t)r0 * SS + j0;
        const float* bp = puc + (size_t)r1 * SS + j0;
        #pragma unroll
        for (int k = 0; k < 4; k++) pv[k] = a[k] * (1.0f - w) + bp[k] * w;
    } else if (i >= SS - off_d) {
        int r0, r1; float w;
        interp1d((float)(i - (SS - off_d)), (float)PP, PP, off_d, r0, r1, w);
        const float* a = pdc + (size_t)r0 * SS + j0;
        const float* bp = pdc + (size_t)r1 * SS + j0;
        #pragma unroll
        for (int k = 0; k < 4; k++) pv[k] = a[k] * (1.0f - w) + bp[k] * w;
    } else {
        const int r = i - off_u;
        const float* plr = plc + (size_t)r * (2 * PP);
        const float* prr = prc + (size_t)r * PP;
        #pragma unroll
        for (int k = 0; k < 4; k++) {
            int j = j0 + k;
            float v = 0.0f;
            if (j < off_l) {
                int c0, c1; float w;
                interp1d((float)j, (float)(2 * PP), 2 * PP, off_l, c0, c1, w);
                v = plr[c0] * (1.0f - w) + plr[c1] * w;
            } else if (j >= SS - off_r) {
                int c0, c1; float w;
                interp1d((float)(j - (SS - off_r)), (float)PP, PP, off_r, c0, c1, w);
                v = prr[c0] * (1.0f - w) + prr[c1] * w;
            }
            pv[k] = v;
        }
    }
    size_t base = ((size_t)(b * 3 + c) * TT) * (SS * SS) + (size_t)i * SS + j0;
    #pragma unroll
    for (int t = 0; t < TT; t++) {
        size_t off = base + (size_t)t * (SS * SS);
        float4 xv = *reinterpret_cast<const float4*>(x + off);
        float4 ov;
        ov.x = xv.x + pv[0]; ov.y = xv.y + pv[1];
        ov.z = xv.z + pv[2]; ov.w = xv.w + pv[3];
        *reinterpret_cast<float4*>(out + off) = ov;
    }
}

extern "C" void kernel_launch(void* const* d_in, const int* in_sizes, int n_in,
                              void* d_out, int out_size, void* d_ws, size_t ws_size,
                              hipStream_t stream) {
    const float* x  = (const float*)d_in[0];
    const float* pu = (const float*)d_in[1];
    const float* pd = (const float*)d_in[2];
    const float* pl = (const float*)d_in[3];
    const float* pr = (const float*)d_in[4];
    const int* cam  = (const int*)d_in[5];
    const int* orr  = (const int*)d_in[6];
    const int* od   = (const int*)d_in[7];
    float* out = (float*)d_out;

    const size_t prompt_bytes = (size_t)BB * 3 * SS * SS * sizeof(float);  // 2.4 MB

    if (ws_size >= prompt_bytes) {
        float* prompt = (float*)d_ws;
        const int total_p = BB * 3 * SS * (SS / 4);      // 150528
        prompt_build_kernel<<<(total_p + 255) / 256, 256, 0, stream>>>(
            pu, pd, pl, pr, cam, orr, od, prompt);
        const int total_s = BB * 3 * TT * SS * (SS / 4); // 2,408,448 threads
        stream_add_kernel<<<(total_s + 255) / 256, 256, 0, stream>>>(x, prompt, out);
    } else {
        const int total = BB * 3 * SS * (SS / 4);
        fused_kernel<<<(total + 255) / 256, 256, 0, stream>>>(
            x, pu, pd, pl, pr, cam, orr, od, out);
    }
}